// Round 1
// baseline (34.960 us; speedup 1.0000x reference)
//
#include <hip/hip_runtime.h>
#include <math.h>

// Plan + sample for TemporalSamplingUpSampler.
// out[0, c, t] = A[c, seg(t)] * w(t), C=256, K=256, T=131072 (sizes taken from in_sizes).
//
// Kernel 1 (plan, 1 block x 256 thr):
//   Lp = T * softmax(L)  (double precision, cast to f32 to mirror jax f32 result)
//   r[k] = max(rint(Lp[k]), 0); total = sum r; l_max = int(max(Lp)+0.5)
//   cum[] = exclusive prefix; s[k] = l_max/Lp[k]; t[k] = (l_max-Lp[k])/Lp[k]  (f32, as reference)
// Kernel 2 (sample): per column t: j = min(floor(t * (total/T)), total-1)  (double, mirrors numpy),
//   seg = first k with cum[k+1] > j, loc = j - cum[seg],
//   x = (2*loc+1)/l_max - 1; xs = s*x + t; p = ((xs+1)*100-1)/2; bilinear edge weight w.
//   Then out[c*T + t] = A[c*K + seg] * w for all c, float4 stores.

#define KMAX 256

__device__ int   g_hdr[2];        // total, l_max
__device__ int   g_cum[KMAX + 1];
__device__ float g_s[KMAX];
__device__ float g_t[KMAX];

__global__ __launch_bounds__(256) void plan_kernel(const float* __restrict__ L, int K, int T) {
    __shared__ float  sf[256];
    __shared__ double sd[256];
    __shared__ int    si[256];
    const int tid = threadIdx.x;

    float Lv = (tid < K) ? L[tid] : -INFINITY;

    // max(L)
    sf[tid] = Lv;
    __syncthreads();
    for (int off = 128; off > 0; off >>= 1) {
        if (tid < off) sf[tid] = fmaxf(sf[tid], sf[tid + off]);
        __syncthreads();
    }
    const float maxL = sf[0];
    __syncthreads();

    // sum(exp(L - max)) in double
    const double e = (tid < K) ? exp((double)Lv - (double)maxL) : 0.0;
    sd[tid] = e;
    __syncthreads();
    for (int off = 128; off > 0; off >>= 1) {
        if (tid < off) sd[tid] += sd[tid + off];
        __syncthreads();
    }
    const double S = sd[0];
    __syncthreads();

    // Lp as f32 (mirror jax f32 softmax result)
    const float Lp = (tid < K) ? (float)((double)T * e / S) : 0.0f;

    // l_max = int(max(Lp) + 0.5)  (double add + trunc, mirroring numpy f64)
    sf[tid] = Lp;   // inactive lanes hold 0, Lp > 0 for active ones
    __syncthreads();
    for (int off = 128; off > 0; off >>= 1) {
        if (tid < off) sf[tid] = fmaxf(sf[tid], sf[tid + off]);
        __syncthreads();
    }
    const int l_max = (int)((double)sf[0] + 0.5);
    __syncthreads();

    // r[k] = max(rint(Lp), 0)   (rintf = round-to-nearest-even, == np.rint)
    int r = 0;
    if (tid < K) {
        r = (int)rintf(Lp);
        if (r < 0) r = 0;
    }

    // inclusive prefix sum over 256 entries (entries >= K are 0)
    si[tid] = r;
    __syncthreads();
    for (int off = 1; off < 256; off <<= 1) {
        int add = (tid >= off) ? si[tid - off] : 0;
        __syncthreads();
        si[tid] += add;
        __syncthreads();
    }

    if (tid == 0) {
        g_cum[0] = 0;
        g_hdr[0] = si[255];   // total
        g_hdr[1] = l_max;
    }
    if (tid < K) {
        g_cum[tid + 1] = si[tid];
        const float fl = (float)l_max;
        g_s[tid] = fl / Lp;
        g_t[tid] = (fl - Lp) / Lp;
    }
}

__global__ __launch_bounds__(256) void sample_kernel(const float* __restrict__ A,
                                                     float* __restrict__ out,
                                                     int K, int C, int T) {
    __shared__ int   s_cum[KMAX + 1];
    __shared__ int   s_seg[256];
    __shared__ float s_w[256];
    const int tid = threadIdx.x;
    const int t0  = blockIdx.x * 256;

    const int total = g_hdr[0];
    const int l_max = g_hdr[1];

    for (int i = tid; i <= K; i += 256) s_cum[i] = g_cum[i];
    __syncthreads();

    // one column per thread: slot j, segment, local offset, edge weight
    {
        const int t = t0 + tid;
        int   seg = 0;
        float w   = 0.0f;
        if (t < T) {
            const double ratio = (double)total / (double)T;
            int j = (int)floor((double)t * ratio);
            if (j > total - 1) j = total - 1;
            if (j < 0) j = 0;

            int lo = 0, hi = K - 1;
            while (lo < hi) {
                const int mid = (lo + hi) >> 1;
                if (s_cum[mid + 1] > j) hi = mid; else lo = mid + 1;
            }
            seg = lo;
            const int loc = j - s_cum[seg];

            const float x  = (2.0f * (float)loc + 1.0f) / (float)l_max - 1.0f;
            const float xs = g_s[seg] * x + g_t[seg];
            const float p  = ((xs + 1.0f) * 100.0f - 1.0f) * 0.5f;
            const float p0 = floorf(p);
            const float w1 = p - p0;
            if (p0 >= 0.0f && p0 <= 99.0f)  w += 1.0f - w1;   // in0 * (1-w1)
            if (p0 >= -1.0f && p0 <= 98.0f) w += w1;          // in1 * w1
        }
        s_seg[tid] = seg;
        s_w[tid]   = w;
    }
    __syncthreads();

    // stream the 256 (cols) x C tile: float4 along t, 4 channel-rows per pass
    const int q  = tid & 63;        // quad of columns
    const int cs = tid >> 6;        // channel sub-row 0..3
    const int tq = t0 + q * 4;

    const int s0 = s_seg[q * 4 + 0], s1 = s_seg[q * 4 + 1];
    const int s2 = s_seg[q * 4 + 2], s3 = s_seg[q * 4 + 3];
    const float w0 = s_w[q * 4 + 0], w1 = s_w[q * 4 + 1];
    const float w2 = s_w[q * 4 + 2], w3 = s_w[q * 4 + 3];

    if (tq + 3 < T) {
        for (int cb = 0; cb < C; cb += 4) {
            const int c = cb + cs;
            const float* Ar = A + (size_t)c * K;
            float4 v;
            v.x = Ar[s0] * w0;
            v.y = Ar[s1] * w1;
            v.z = Ar[s2] * w2;
            v.w = Ar[s3] * w3;
            *(float4*)(out + (size_t)c * T + tq) = v;
        }
    } else {
        const int segs[4] = {s0, s1, s2, s3};
        const float ws[4] = {w0, w1, w2, w3};
        for (int cb = 0; cb < C; cb += 4) {
            const int c = cb + cs;
            const float* Ar = A + (size_t)c * K;
            for (int u = 0; u < 4; ++u) {
                const int t = tq + u;
                if (t < T) out[(size_t)c * T + t] = Ar[segs[u]] * ws[u];
            }
        }
    }
}

extern "C" void kernel_launch(void* const* d_in, const int* in_sizes, int n_in,
                              void* d_out, int out_size, void* d_ws, size_t ws_size,
                              hipStream_t stream) {
    const float* A = (const float*)d_in[0];
    const float* L = (const float*)d_in[1];

    const int K = in_sizes[1];                 // 256
    const int C = in_sizes[0] / K;             // 256
    const int T = out_size / C;                // 131072

    plan_kernel<<<1, 256, 0, stream>>>(L, K, T);

    const int nblk = (T + 255) / 256;
    sample_kernel<<<nblk, 256, 0, stream>>>(A, (float*)d_out, K, C, T);
}

// Round 2
// 31.070 us; speedup vs baseline: 1.1252x; 1.1252x over previous
//
#include <hip/hip_runtime.h>
#include <math.h>

// Fused plan+sample for TemporalSamplingUpSampler.
// out[0, c, t] = A[c, seg(t)] * w(t); C=256, K=256, T=131072 (from in_sizes).
//
// Every block recomputes the (cheap, deterministic) plan from L, then streams
// its 256-column x C output tile with non-temporal float4 stores.
// Plan math mirrors the reference exactly (verified passing in R0):
//   Lp = f32( T * exp(L-max) / sum )  computed in double  (jax f32 softmax proxy)
//   r  = max(rint(Lp),0); total = sum r; l_max = int(max(Lp)+0.5)
//   j(t) = min(floor(t * (total/T)), total-1)   in double (numpy)
//   seg = bsearch(cum, j); loc = j - cum[seg]
//   x = (2*loc+1)/l_max - 1; xs = s*x + tt; p = ((xs+1)*100-1)/2
//   w = (1-frac)*[p0 in 0..99] + frac*[p0 in -1..98]

#define KMAX 256

typedef float f32x4 __attribute__((ext_vector_type(4)));

__global__ __launch_bounds__(256) void fused_kernel(const float* __restrict__ A,
                                                    const float* __restrict__ L,
                                                    float* __restrict__ out,
                                                    int K, int C, int T) {
    __shared__ float  s_s[KMAX];
    __shared__ float  s_t[KMAX];
    __shared__ int    s_cum[KMAX + 1];
    __shared__ int    s_seg[256];
    __shared__ float  s_w[256];
    __shared__ double sd[4];
    __shared__ float  sf[4];
    __shared__ int    si[4];

    const int tid  = threadIdx.x;
    const int lane = tid & 63;
    const int wid  = tid >> 6;

    const float Lv = (tid < K) ? L[tid] : -INFINITY;

    // ---- max(L): wave shfl-reduce, then 4 wave partials ----
    float m = Lv;
    #pragma unroll
    for (int o = 32; o > 0; o >>= 1) m = fmaxf(m, __shfl_xor(m, o));
    if (lane == 0) sf[wid] = m;
    __syncthreads();
    const float maxL = fmaxf(fmaxf(sf[0], sf[1]), fmaxf(sf[2], sf[3]));

    // ---- sum(exp(L-max)) in double ----
    const double e = (tid < K) ? exp((double)Lv - (double)maxL) : 0.0;
    double se = e;
    #pragma unroll
    for (int o = 32; o > 0; o >>= 1) se += __shfl_xor(se, o);
    if (lane == 0) sd[wid] = se;
    __syncthreads();
    const double S = sd[0] + sd[1] + sd[2] + sd[3];

    // Lp as f32 (mirrors jax f32 softmax result)
    const float Lp = (tid < K) ? (float)((double)T * e / S) : 0.0f;

    // ---- l_max = int(max(Lp) + 0.5) ----
    float mp = (tid < K) ? Lp : 0.0f;
    #pragma unroll
    for (int o = 32; o > 0; o >>= 1) mp = fmaxf(mp, __shfl_xor(mp, o));
    __syncthreads();              // sf reuse: everyone is done reading phase-1 sf
    if (lane == 0) sf[wid] = mp;
    __syncthreads();
    const int l_max = (int)((double)fmaxf(fmaxf(sf[0], sf[1]), fmaxf(sf[2], sf[3])) + 0.5);

    // ---- r = max(rint(Lp),0); inclusive scan -> cum ----
    int r = 0;
    if (tid < K) {
        r = (int)rintf(Lp);
        if (r < 0) r = 0;
    }
    int v = r;
    #pragma unroll
    for (int o = 1; o < 64; o <<= 1) {
        const int n = __shfl_up(v, o);
        if (lane >= o) v += n;
    }
    if (lane == 63) si[wid] = v;
    __syncthreads();
    int offset = 0;
    for (int w = 0; w < wid; ++w) offset += si[w];
    const int total = si[0] + si[1] + si[2] + si[3];
    if (tid == 0) s_cum[0] = 0;
    if (tid < K) {
        s_cum[tid + 1] = v + offset;
        const float fl = (float)l_max;
        s_s[tid] = fl / Lp;
        s_t[tid] = (fl - Lp) / Lp;
    }
    __syncthreads();

    // ---- per-column: slot j, segment, local offset, edge weight ----
    const int t0 = blockIdx.x * 256;
    {
        const int t = t0 + tid;
        int   seg = 0;
        float w   = 0.0f;
        if (t < T) {
            const double ratio = (double)total / (double)T;
            int j = (int)floor((double)t * ratio);
            if (j > total - 1) j = total - 1;
            if (j < 0) j = 0;

            int lo = 0, hi = K - 1;
            while (lo < hi) {
                const int mid = (lo + hi) >> 1;
                if (s_cum[mid + 1] > j) hi = mid; else lo = mid + 1;
            }
            seg = lo;
            const int loc = j - s_cum[seg];

            const float x  = (2.0f * (float)loc + 1.0f) / (float)l_max - 1.0f;
            const float xs = s_s[seg] * x + s_t[seg];
            const float p  = ((xs + 1.0f) * 100.0f - 1.0f) * 0.5f;
            const float p0 = floorf(p);
            const float w1 = p - p0;
            if (p0 >= 0.0f && p0 <= 99.0f)  w += 1.0f - w1;
            if (p0 >= -1.0f && p0 <= 98.0f) w += w1;
        }
        s_seg[tid] = seg;
        s_w[tid]   = w;
    }
    __syncthreads();

    // ---- stream the 256-col x C tile: float4 along t, 4 channel-rows/pass ----
    const int q  = tid & 63;
    const int cs = tid >> 6;
    const int tq = t0 + q * 4;

    const int   s0 = s_seg[q * 4 + 0], s1 = s_seg[q * 4 + 1];
    const int   s2 = s_seg[q * 4 + 2], s3 = s_seg[q * 4 + 3];
    const float w0 = s_w[q * 4 + 0],   w1 = s_w[q * 4 + 1];
    const float w2 = s_w[q * 4 + 2],   w3 = s_w[q * 4 + 3];

    if (tq + 3 < T) {
        #pragma unroll 4
        for (int cb = 0; cb < C; cb += 4) {
            const int c = cb + cs;
            const float* __restrict__ Ar = A + (size_t)c * K;
            f32x4 vv;
            vv.x = Ar[s0] * w0;
            vv.y = Ar[s1] * w1;
            vv.z = Ar[s2] * w2;
            vv.w = Ar[s3] * w3;
            __builtin_nontemporal_store(vv, (f32x4*)(out + (size_t)c * T + tq));
        }
    } else {
        const int   segs[4] = {s0, s1, s2, s3};
        const float ws[4]   = {w0, w1, w2, w3};
        for (int cb = 0; cb < C; cb += 4) {
            const int c = cb + cs;
            const float* __restrict__ Ar = A + (size_t)c * K;
            for (int u = 0; u < 4; ++u) {
                const int t = tq + u;
                if (t < T) out[(size_t)c * T + t] = Ar[segs[u]] * ws[u];
            }
        }
    }
}

extern "C" void kernel_launch(void* const* d_in, const int* in_sizes, int n_in,
                              void* d_out, int out_size, void* d_ws, size_t ws_size,
                              hipStream_t stream) {
    const float* A = (const float*)d_in[0];
    const float* L = (const float*)d_in[1];

    const int K = in_sizes[1];                 // 256
    const int C = in_sizes[0] / K;             // 256
    const int T = out_size / C;                // 131072

    const int nblk = (T + 255) / 256;
    fused_kernel<<<nblk, 256, 0, stream>>>(A, L, (float*)d_out, K, C, T);
}